// Round 1
// baseline (416.079 us; speedup 1.0000x reference)
//
#include <hip/hip_runtime.h>
#include <hip/hip_bf16.h>

// AlignmentContrastiveLoss on MI355X.
// Pipeline:
//   K1 normalize_pack: fp32 L2-normalize rows of im_set/s_seq, drop CLS/special
//      tokens, cast to bf16, write zero-padded im' [256][48][1024], s' [256][32][1024].
//   K2 gemm_scores: bf16 MFMA GEMM (M=96 rows = 2 images x 48, N=256 cols = 8
//      sentences x 32, K=1024) with fused masked max-over-regions /
//      sum-over-words epilogue -> scores[256][256] fp32.
//   K3 loss_kernel: contrastive loss with hardest negatives -> scalar.

typedef __attribute__((ext_vector_type(8))) short bf16x8;
typedef __attribute__((ext_vector_type(4))) float f32x4;

#define NB   256
#define DIM  1024
#define LI   36     // valid image regions after dropping CLS
#define LIP  48     // padded to 3 x 16
#define LS   30     // valid words after dropping first + last two
#define LSP  32     // padded to 2 x 16
#define AST  72     // LDS row stride in bf16 elems (64 + 8 pad -> 2-way bank alias only)

static __device__ inline ushort f2bf(float x) {
    union { __hip_bfloat16 h; ushort u; } cvt;
    cvt.h = __float2bfloat16(x);
    return cvt.u;
}

// One wave per output row. Rows 0..256*48-1 -> im', rest -> s'.
__global__ __launch_bounds__(256) void normalize_pack(
    const float* __restrict__ im, const float* __restrict__ sq,
    short* __restrict__ imp, short* __restrict__ sp)
{
    const int gw   = (blockIdx.x * 256 + threadIdx.x) >> 6;
    const int lane = threadIdx.x & 63;
    const int NIM  = NB * LIP;

    const float* src = nullptr;
    short* dst;
    if (gw < NIM) {
        int b = gw / LIP, i = gw - b * LIP;
        dst = imp + (size_t)gw * DIM;
        if (i < LI) src = im + ((size_t)b * 37 + i + 1) * DIM;   // drop CLS region 0
    } else {
        int g2 = gw - NIM;
        int b = g2 / LSP, j = g2 - b * LSP;
        dst = sp + (size_t)g2 * DIM;
        if (j < LS) src = sq + ((size_t)b * 33 + j + 1) * DIM;   // rows 1..30 of 33
    }

    if (src) {
        const float4* s4 = (const float4*)src;
        float4 v[4];
        float ss = 0.f;
        #pragma unroll
        for (int t = 0; t < 4; ++t) {
            float4 x = s4[lane + 64 * t];
            v[t] = x;
            ss += x.x * x.x + x.y * x.y + x.z * x.z + x.w * x.w;
        }
        #pragma unroll
        for (int o = 32; o >= 1; o >>= 1) ss += __shfl_xor(ss, o, 64);
        float scale = 1.0f / fmaxf(sqrtf(ss), 1e-12f);
        ushort4* d4 = (ushort4*)dst;
        #pragma unroll
        for (int t = 0; t < 4; ++t) {
            float4 x = v[t];
            ushort4 o;
            o.x = f2bf(x.x * scale);
            o.y = f2bf(x.y * scale);
            o.z = f2bf(x.z * scale);
            o.w = f2bf(x.w * scale);
            d4[lane + 64 * t] = o;
        }
    } else {
        // padding row: zero it (ws is re-poisoned before every launch)
        uint4 z = {0u, 0u, 0u, 0u};
        uint4* d4 = (uint4*)dst;   // 1024 bf16 = 128 uint4
        d4[lane] = z;
        d4[lane + 64] = z;
    }
}

// Block: 256 threads = 4 waves. blockIdx.x -> pair of images (b0=2*x),
// blockIdx.y -> 8 sentences (c0=8*y). Wave w owns N-tiles 4w..4w+3
// (= sentences c0+2w, c0+2w+1), all 6 M-tiles -> its 4 score cells are
// wave-private.
__global__ __launch_bounds__(256) void gemm_scores(
    const short* __restrict__ imp, const short* __restrict__ sp,
    const int* __restrict__ im_len, const int* __restrict__ s_len,
    float* __restrict__ scores)
{
    __shared__ short As[96 * AST];    // 13.8 KB
    __shared__ short Bs[256 * AST];   // 36.9 KB

    const int tid  = threadIdx.x;
    const int wave = tid >> 6;
    const int lane = tid & 63;
    const int q    = lane >> 4;
    const int l15  = lane & 15;
    const int b0   = blockIdx.x * 2;
    const int c0   = blockIdx.y * 8;

    f32x4 acc[6][4];
    #pragma unroll
    for (int mt = 0; mt < 6; ++mt)
        #pragma unroll
        for (int t = 0; t < 4; ++t)
            acc[mt][t] = (f32x4){0.f, 0.f, 0.f, 0.f};

    const uint4* gA = (const uint4*)imp;  // 8 bf16 per uint4, row = 128 uint4
    const uint4* gB = (const uint4*)sp;

    for (int k0 = 0; k0 < DIM; k0 += 64) {
        const int kc0 = k0 >> 3;
        // stage A: 96 rows x 8 chunks = 768 16B-chunks, 3/thread
        #pragma unroll
        for (int it = 0; it < 3; ++it) {
            int cid = it * 256 + tid;
            int row = cid >> 3, kch = cid & 7;
            uint4 v = gA[(b0 * LIP + row) * 128 + kc0 + kch];
            *(uint4*)&As[row * AST + kch * 8] = v;
        }
        // stage B: 256 rows x 8 chunks = 2048 chunks, 8/thread
        #pragma unroll
        for (int it = 0; it < 8; ++it) {
            int cid = it * 256 + tid;
            int row = cid >> 3, kch = cid & 7;
            uint4 v = gB[(c0 * LSP + row) * 128 + kc0 + kch];
            *(uint4*)&Bs[row * AST + kch * 8] = v;
        }
        __syncthreads();
        #pragma unroll
        for (int g = 0; g < 2; ++g) {
            bf16x8 af[6], bfr[4];
            #pragma unroll
            for (int mt = 0; mt < 6; ++mt)
                af[mt] = *(const bf16x8*)&As[(mt * 16 + l15) * AST + g * 32 + q * 8];
            #pragma unroll
            for (int t = 0; t < 4; ++t)
                bfr[t] = *(const bf16x8*)&Bs[((wave * 4 + t) * 16 + l15) * AST + g * 32 + q * 8];
            #pragma unroll
            for (int mt = 0; mt < 6; ++mt)
                #pragma unroll
                for (int t = 0; t < 4; ++t)
                    acc[mt][t] = __builtin_amdgcn_mfma_f32_16x16x32_bf16(
                        af[mt], bfr[t], acc[mt][t], 0, 0, 0);
        }
        __syncthreads();
    }

    // Fused epilogue. C/D layout: lane holds col = lane&15, row = (lane>>4)*4 + r.
    const int iml0 = im_len[b0] - 1;       // in [9, 36]
    const int iml1 = im_len[b0 + 1] - 1;

    float sc[2][2] = {{0.f, 0.f}, {0.f, 0.f}};
    #pragma unroll
    for (int t = 0; t < 4; ++t) {
        const int nt = wave * 4 + t;
        const int c  = c0 + (nt >> 1);
        const int sl = s_len[c] - 3;                 // valid words, in [5, 30]
        const int jj = (nt & 1) * 16 + l15;          // word index within sentence
        const bool jv = (jj < sl);
        #pragma unroll
        for (int bb = 0; bb < 2; ++bb) {
            const int il = bb ? iml1 : iml0;
            float m = -3.4e38f;
            #pragma unroll
            for (int mt3 = 0; mt3 < 3; ++mt3) {
                #pragma unroll
                for (int r = 0; r < 4; ++r) {
                    int i = mt3 * 16 + q * 4 + r;    // global region index
                    float v = acc[bb * 3 + mt3][t][r];
                    if (i < il) m = fmaxf(m, v);     // pads & masked rows excluded
                }
            }
            // combine the 4 row-quads -> full max over i for column l15
            m = fmaxf(m, __shfl_xor(m, 16, 64));
            m = fmaxf(m, __shfl_xor(m, 32, 64));
            // reference: masked entries are 0 and participate in the max only
            // when some region is masked (il < 36)
            if (il < LI) m = fmaxf(m, 0.f);
            float v = (q == 0 && jv) ? m : 0.f;      // count each column once
            #pragma unroll
            for (int off = 32; off >= 1; off >>= 1) v += __shfl_xor(v, off, 64);
            sc[bb][t >> 1] += v;
        }
    }
    if (lane == 0) {
        #pragma unroll
        for (int bb = 0; bb < 2; ++bb)
            #pragma unroll
            for (int h = 0; h < 2; ++h)
                scores[(b0 + bb) * NB + c0 + wave * 2 + h] = sc[bb][h];
    }
}

// cost_s[t] = max_{c!=t} relu(M + s[t][c] - s[t][t]);
// cost_im[t] = max_{b!=t} relu(M + s[b][t] - s[t][t]); loss = sum of both.
__global__ __launch_bounds__(256) void loss_kernel(
    const float* __restrict__ sc, float* __restrict__ out)
{
    const int t = threadIdx.x;
    const float dt = sc[t * (NB + 1)];
    float rowmax = 0.f, colmax = 0.f;
    for (int k = 0; k < NB; ++k) {
        if (k != t) {
            rowmax = fmaxf(rowmax, 0.2f + sc[t * NB + k] - dt);
            colmax = fmaxf(colmax, 0.2f + sc[k * NB + t] - dt);
        }
    }
    rowmax = fmaxf(rowmax, 0.f);   // relu == max with the zeroed diagonal
    colmax = fmaxf(colmax, 0.f);
    float v = rowmax + colmax;
    __shared__ float red[4];
    #pragma unroll
    for (int o = 32; o >= 1; o >>= 1) v += __shfl_xor(v, o, 64);
    if ((t & 63) == 0) red[t >> 6] = v;
    __syncthreads();
    if (t == 0) out[0] = red[0] + red[1] + red[2] + red[3];
}

extern "C" void kernel_launch(void* const* d_in, const int* in_sizes, int n_in,
                              void* d_out, int out_size, void* d_ws, size_t ws_size,
                              hipStream_t stream) {
    const float* im_set = (const float*)d_in[0];
    const float* s_seq  = (const float*)d_in[1];
    const int*   im_len = (const int*)d_in[2];
    const int*   s_len  = (const int*)d_in[3];
    float* out = (float*)d_out;

    char* ws = (char*)d_ws;
    const size_t imp_bytes = (size_t)NB * LIP * DIM * 2;   // 25.2 MB
    const size_t sp_bytes  = (size_t)NB * LSP * DIM * 2;   // 16.8 MB
    short* imp    = (short*)ws;
    short* sp     = (short*)(ws + imp_bytes);
    float* scores = (float*)(ws + imp_bytes + sp_bytes);   // 256 KB

    // 256*48 + 256*32 = 20480 rows, one wave each -> 5120 blocks
    normalize_pack<<<5120, 256, 0, stream>>>(im_set, s_seq, imp, sp);

    dim3 grid(NB / 2, NB / 8);
    gemm_scores<<<grid, 256, 0, stream>>>(imp, sp, im_len, s_len, scores);

    loss_kernel<<<1, 256, 0, stream>>>(scores, out);
}